// Round 1
// baseline (793.671 us; speedup 1.0000x reference)
//
#include <hip/hip_runtime.h>
#include <math.h>

#define NB 32
#define HID 2560
#define NHD 32
#define NKVH 8
#define HD 80
#define LL 4096
#define QKVC 3840          // NH*D + 2*NKV*D
#define KOFF 2560          // q size
#define VOFF 3200          // q size + kv size
#define SCALE_F 0.11180339887498949f   // 80^-0.5

// ---------------------------------------------------------------------------
// GEMM: Y[32,NC] += X[32,2560] @ W[2560,NC]; grid (NC/256, 16 k-chunks of 160)
// block 256: 64 float4-cols x 4 wave row-groups (8 rows each).
// W staged in LDS (float4, conflict-free); X read via wave-uniform scalar loads.
// ---------------------------------------------------------------------------
template<int NC>
__global__ __launch_bounds__(256)
void gemm32_kernel(const float* __restrict__ X, const float* __restrict__ W,
                   float* __restrict__ Y)
{
  const int t = threadIdx.x;
  const int c = t & 63;                                   // float4 col in tile
  const int rq = __builtin_amdgcn_readfirstlane(t >> 6);  // wave-uniform row grp
  const int cbase = blockIdx.x * 256;
  const int kbase = blockIdx.y * 160;

  __shared__ float4 wt[32 * 64];   // 32 k-rows x 64 float4 cols = 32 KB

  float4 acc[8];
#pragma unroll
  for (int r = 0; r < 8; ++r) acc[r] = make_float4(0.f, 0.f, 0.f, 0.f);

  const float* Xb = X + rq * 8 * HID + kbase;   // scalar base (8 rows)

  for (int kt = 0; kt < 160; kt += 32) {
#pragma unroll
    for (int i = 0; i < 8; ++i) {
      int idx = t + i * 256;                    // 0..2047
      int kr = idx >> 6, cc = idx & 63;
      wt[idx] = *(const float4*)(W + (size_t)(kbase + kt + kr) * NC + cbase + cc * 4);
    }
    __syncthreads();
#pragma unroll 4
    for (int k = 0; k < 32; ++k) {
      float4 wv = wt[k * 64 + c];
#pragma unroll
      for (int r = 0; r < 8; ++r) {
        float h = Xb[r * HID + kt + k];         // uniform -> s_load
        acc[r].x += h * wv.x; acc[r].y += h * wv.y;
        acc[r].z += h * wv.z; acc[r].w += h * wv.w;
      }
    }
    __syncthreads();
  }
#pragma unroll
  for (int r = 0; r < 8; ++r) {
    float* yp = Y + (size_t)(rq * 8 + r) * NC + cbase + c * 4;
    atomicAdd(yp + 0, acc[r].x);
    atomicAdd(yp + 1, acc[r].y);
    atomicAdd(yp + 2, acc[r].z);
    atomicAdd(yp + 3, acc[r].w);
  }
}

// ---------------------------------------------------------------------------
// RoPE in-place on q and k sections of qkv. grid 32 (batch), block 256.
// Pair (j, j+10) of first 20 dims rotated by pos * BASE^(-2j/20).
// ---------------------------------------------------------------------------
__global__ void rope_kernel(const int* __restrict__ pos, float* __restrict__ qkv)
{
  const int b = blockIdx.x;
  const float pf = (float)pos[b];
  for (int idx = threadIdx.x; idx < 400; idx += 256) {   // 40 heads x 10 pairs
    int h = idx / 10, j = idx % 10;
    int off = (h < NHD) ? (b * QKVC + h * HD)
                        : (b * QKVC + KOFF + (h - NHD) * HD);
    float e = (float)(2 * j) / 20.0f;
    float invf = 1.0f / powf(10000.0f, e);
    float ang = pf * invf;
    float sn, cs;
    sincosf(ang, &sn, &cs);
    float x1 = qkv[off + j], x2 = qkv[off + j + 10];
    qkv[off + j]      = x1 * cs - x2 * sn;
    qkv[off + j + 10] = x2 * cs + x1 * sn;
  }
}

// ---------------------------------------------------------------------------
// Attention: one block per (b, kv). 640 threads. K staged in LDS (pad 21 f4),
// V read direct-from-global with lane multicast. Online softmax per
// (g, wave-half) => shuffle-only reductions, combined at the end.
// ---------------------------------------------------------------------------
__global__ __launch_bounds__(640)
void attn_kernel(const float* __restrict__ kc, const float* __restrict__ vc,
                 const float* __restrict__ qkv, float* __restrict__ attnout)
{
  const int t = threadIdx.x;
  const int b = blockIdx.x >> 3;
  const int kv = blockIdx.x & 7;

  __shared__ float4 kbuf[128 * 21];       // 43008 B, padded rows (bank-clean)
  __shared__ float4 q4[80];               // [g*20 + d4]
  __shared__ float plds[4 * 132];         // p[g][l], padded row
  __shared__ float mstate[8], sumstate[8], alpha_s[8], pnew[4], wfac[8];

  if (t < 8) { mstate[t] = -1e30f; sumstate[t] = 0.0f; }
  if (t < 80) {
    const float* qp = qkv + (size_t)b * QKVC + (kv * 4 + t / 20) * HD;
    q4[t] = *(const float4*)(qp + (t % 20) * 4);
  }

  const float* kb = kc + (size_t)blockIdx.x * (LL * HD);
  const float* vb = vc + (size_t)blockIdx.x * (LL * HD);

  const int srow = t / 20;                // staging: 32 rows per pass
  const int sd4  = t % 20;

  float4 kpre[4];
#pragma unroll
  for (int i = 0; i < 4; ++i)
    kpre[i] = *(const float4*)(kb + (size_t)(srow + 32 * i) * HD + sd4 * 4);

  const int qg = t >> 7;                  // QK role (t < 512): head
  const int ql = t & 127;                 //                    key in tile
  const int psub = t / 80;                // PV role: l-16-slice 0..7
  const int pg   = (t % 80) / 20;         //          head
  const int pd4  = t % 20;                //          float4 dim
  const int phalf = psub >> 2;            //          wave-half of tile

  float4 acc = make_float4(0.f, 0.f, 0.f, 0.f);

  __syncthreads();

  for (int tile = 0; tile < 32; ++tile) {
#pragma unroll
    for (int i = 0; i < 4; ++i)
      kbuf[(srow + 32 * i) * 21 + sd4] = kpre[i];
    __syncthreads();
    if (tile < 31) {                      // prefetch next K-tile into regs
#pragma unroll
      for (int i = 0; i < 4; ++i)
        kpre[i] = *(const float4*)(kb + (size_t)((tile + 1) * 128 + srow + 32 * i) * HD + sd4 * 4);
    }
    // ---- QK + online softmax (per wave-half, shuffle-only reductions) ----
    if (t < 512) {
      float ss = 0.f;
#pragma unroll
      for (int d4 = 0; d4 < 20; ++d4) {
        float4 kk = kbuf[ql * 21 + d4];
        float4 qq = q4[qg * 20 + d4];
        ss += kk.x * qq.x + kk.y * qq.y + kk.z * qq.z + kk.w * qq.w;
      }
      float s = ss * SCALE_F;
      float wm = s;
#pragma unroll
      for (int off = 32; off >= 1; off >>= 1)
        wm = fmaxf(wm, __shfl_xor(wm, off, 64));
      const int st = qg * 2 + ((t >> 6) & 1);
      float m_old = mstate[st];
      float m_new = fmaxf(m_old, wm);
      float p = __expf(s - m_new);
      plds[qg * 132 + ql] = p;
      float wsum = p;
#pragma unroll
      for (int off = 32; off >= 1; off >>= 1)
        wsum += __shfl_xor(wsum, off, 64);
      if ((t & 63) == 0) {                // lane 0 of each of waves 0..7
        float a = __expf(m_old - m_new);
        sumstate[st] = sumstate[st] * a + wsum;
        mstate[st] = m_new;
        alpha_s[st] = a;
      }
    }
    __syncthreads();
    // ---- PV: v direct from global (multicast), p from LDS ----
    {
      float a = alpha_s[pg * 2 + phalf];
      acc.x *= a; acc.y *= a; acc.z *= a; acc.w *= a;
      const int lb = psub * 16;
      const float* vrow = vb + (size_t)(tile * 128 + lb) * HD + pd4 * 4;
#pragma unroll
      for (int i = 0; i < 16; ++i) {
        float pv = plds[pg * 132 + lb + i];
        float4 vv = *(const float4*)(vrow + (size_t)i * HD);
        acc.x += pv * vv.x; acc.y += pv * vv.y;
        acc.z += pv * vv.z; acc.w += pv * vv.w;
      }
    }
    __syncthreads();
  }

  // ---- new token (l = 4096): k/v from qkv scratch, update half 0 ----
  if (t < 20)
    kbuf[t] = *(const float4*)(qkv + (size_t)b * QKVC + KOFF + kv * HD + t * 4);
  __syncthreads();
  if (t < 4) {
    float ss = 0.f;
#pragma unroll
    for (int d4 = 0; d4 < 20; ++d4) {
      float4 kk = kbuf[d4];
      float4 qq = q4[t * 20 + d4];
      ss += kk.x * qq.x + kk.y * qq.y + kk.z * qq.z + kk.w * qq.w;
    }
    ss *= SCALE_F;
    const int st = t * 2;
    float m_old = mstate[st];
    float m_new = fmaxf(m_old, ss);
    float a = __expf(m_old - m_new);
    float pn = __expf(ss - m_new);
    sumstate[st] = sumstate[st] * a + pn;
    mstate[st] = m_new;
    alpha_s[st] = a;
    pnew[t] = pn;
  }
  __syncthreads();
  if (phalf == 0) {
    float a = alpha_s[pg * 2];
    acc.x *= a; acc.y *= a; acc.z *= a; acc.w *= a;
    if (psub == 0) {
      float pn = pnew[pg];
      float4 vv = *(const float4*)(qkv + (size_t)b * QKVC + VOFF + kv * HD + pd4 * 4);
      acc.x += pn * vv.x; acc.y += pn * vv.y;
      acc.z += pn * vv.z; acc.w += pn * vv.w;
    }
  }
  if (t < 4) {                            // final half-combine weights
    float m0 = mstate[t * 2], m1 = mstate[t * 2 + 1];
    float mf = fmaxf(m0, m1);
    float w0 = __expf(m0 - mf), w1 = __expf(m1 - mf);
    float inv = 1.0f / (sumstate[t * 2] * w0 + sumstate[t * 2 + 1] * w1);
    wfac[t * 2]     = w0 * inv;
    wfac[t * 2 + 1] = w1 * inv;
  }
  __syncthreads();
  {
    float w = wfac[pg * 2 + phalf];
    kbuf[t] = make_float4(acc.x * w, acc.y * w, acc.z * w, acc.w * w);
  }
  __syncthreads();
  if (t < 80) {                           // reduce 8 l-slices, write out
    float4 o = make_float4(0.f, 0.f, 0.f, 0.f);
#pragma unroll
    for (int s = 0; s < 8; ++s) {
      float4 cp = kbuf[s * 80 + t];
      o.x += cp.x; o.y += cp.y; o.z += cp.z; o.w += cp.w;
    }
    const int g = t / 20, d4 = t % 20;
    *(float4*)(attnout + (size_t)b * (NHD * HD) + (kv * 4 + g) * HD + d4 * 4) = o;
  }
}

// ---------------------------------------------------------------------------
extern "C" void kernel_launch(void* const* d_in, const int* in_sizes, int n_in,
                              void* d_out, int out_size, void* d_ws, size_t ws_size,
                              hipStream_t stream)
{
  const int*   positions = (const int*)d_in[0];
  const float* hidden    = (const float*)d_in[1];
  const float* k_cache   = (const float*)d_in[2];
  const float* v_cache   = (const float*)d_in[3];
  const float* w_qkv     = (const float*)d_in[4];
  const float* w_o       = (const float*)d_in[5];
  float* out = (float*)d_out;

  float* qkv     = (float*)d_ws;          // 32*3840 floats
  float* attnout = qkv + NB * QKVC;       // 32*2560 floats

  hipMemsetAsync(qkv, 0, (size_t)NB * QKVC * sizeof(float), stream);
  hipMemsetAsync(out, 0, (size_t)NB * HID * sizeof(float), stream);

  gemm32_kernel<QKVC><<<dim3(QKVC / 256, 16), 256, 0, stream>>>(hidden, w_qkv, qkv);
  rope_kernel<<<NB, 256, 0, stream>>>(positions, qkv);
  attn_kernel<<<NB * NKVH, 640, 0, stream>>>(k_cache, v_cache, qkv, attnout);
  gemm32_kernel<HID><<<dim3(HID / 256, 16), 256, 0, stream>>>(attnout, w_o, out);
}